// Round 3
// baseline (7666.755 us; speedup 1.0000x reference)
//
#include <hip/hip_runtime.h>
#include <hip/hip_bf16.h>
#include <math.h>

#define LSEQ 256
#define BB   64
#define EE   256
#define HH   256
#define TT   16

// ---------------- embedding gather: x0[r][e] = emb[tokens[r]][e] ----------------
__global__ __launch_bounds__(64)
void embed_kernel(const int* __restrict__ tokens, const float* __restrict__ emb,
                  float* __restrict__ x0) {
    int r = blockIdx.x;                       // r = t*B + b, 0..16383
    int tok = tokens[r];
    const float4* src = (const float4*)(emb + (size_t)tok * EE);
    float4* dst = (float4*)(x0 + (size_t)r * EE);
    dst[threadIdx.x] = src[threadIdx.x];      // 64 threads * float4 = 256 floats
}

// -------- transpose-pack W_hh into W2[dl][uq][k][g*64+ul] = w_hh[g*256+uq*64+ul][k] --------
__global__ __launch_bounds__(256)
void transpose_whh_kernel(const float* __restrict__ w0, const float* __restrict__ w1,
                          const float* __restrict__ w2, const float* __restrict__ w3,
                          float* __restrict__ W2) {
    __shared__ float tile[64][65];
    const float* w = blockIdx.z == 0 ? w0 : blockIdx.z == 1 ? w1 : blockIdx.z == 2 ? w2 : w3;
    int k0 = blockIdx.x * 64, n0 = blockIdx.y * 64, tid = threadIdx.x;
    int g  = n0 >> 8;            // gate (n0 is 64-aligned)
    int uq = (n0 >> 6) & 3;      // unit-quarter
    float* out = W2 + (size_t)blockIdx.z * 262144 + (size_t)uq * 65536;
    for (int e = tid; e < 4096; e += 256) {
        int nl = e >> 6, kl = e & 63;                 // read w[n0+nl][k0+kl], lanes kl consecutive
        tile[nl][kl] = w[(size_t)(n0 + nl) * 256 + k0 + kl];
    }
    __syncthreads();
    for (int e = tid; e < 4096; e += 256) {
        int kl = e >> 6, nl = e & 63;                 // write out[k0+kl][g*64+nl], lanes nl consecutive
        out[(size_t)(k0 + kl) * 256 + g * 64 + nl] = tile[nl][kl];
    }
}

// ---------------- zero the scan sync flags (must run every launch for graph replay) ----------------
__global__ __launch_bounds__(256)
void init_flags_kernel(int* __restrict__ flags) {
    flags[threadIdx.x] = 0;
    flags[256 + threadIdx.x] = 0;
}

// ---------------- C[M,N] = A[M,K] @ W[N,K]^T + b1[N] + b2[N] ----------------
__global__ __launch_bounds__(256)
void gemm_bias_kernel(const float* __restrict__ A, const float* __restrict__ W,
                      const float* __restrict__ b1, const float* __restrict__ b2,
                      float* __restrict__ C, int M, int N, int K) {
    const int BK = 16;
    __shared__ float As[BK][128];
    __shared__ float Bs[BK][128];
    int tid = threadIdx.x;
    int bm = blockIdx.x * 128;
    int bn = blockIdx.y * 128;
    int tm = (tid >> 4) << 3;
    int tn = (tid & 15) << 3;
    int lr = tid >> 1;                 // tile row 0..127
    int lc = (tid & 1) << 3;           // col offset 0 or 8
    const float* Ap = A + (size_t)(bm + lr) * K + lc;
    const float* Wpt = W + (size_t)(bn + lr) * K + lc;
    float acc[8][8];
#pragma unroll
    for (int i = 0; i < 8; i++)
#pragma unroll
        for (int j = 0; j < 8; j++) acc[i][j] = 0.f;

    for (int k0 = 0; k0 < K; k0 += BK) {
        float4 a0 = *(const float4*)(Ap + k0);
        float4 a1 = *(const float4*)(Ap + k0 + 4);
        float4 w0 = *(const float4*)(Wpt + k0);
        float4 w1 = *(const float4*)(Wpt + k0 + 4);
        __syncthreads();
        As[lc+0][lr]=a0.x; As[lc+1][lr]=a0.y; As[lc+2][lr]=a0.z; As[lc+3][lr]=a0.w;
        As[lc+4][lr]=a1.x; As[lc+5][lr]=a1.y; As[lc+6][lr]=a1.z; As[lc+7][lr]=a1.w;
        Bs[lc+0][lr]=w0.x; Bs[lc+1][lr]=w0.y; Bs[lc+2][lr]=w0.z; Bs[lc+3][lr]=w0.w;
        Bs[lc+4][lr]=w1.x; Bs[lc+5][lr]=w1.y; Bs[lc+6][lr]=w1.z; Bs[lc+7][lr]=w1.w;
        __syncthreads();
#pragma unroll
        for (int k = 0; k < BK; k++) {
            float av[8], bv[8];
            *(float4*)&av[0] = *(const float4*)&As[k][tm];
            *(float4*)&av[4] = *(const float4*)&As[k][tm+4];
            *(float4*)&bv[0] = *(const float4*)&Bs[k][tn];
            *(float4*)&bv[4] = *(const float4*)&Bs[k][tn+4];
#pragma unroll
            for (int i = 0; i < 8; i++)
#pragma unroll
                for (int j = 0; j < 8; j++) acc[i][j] = fmaf(av[i], bv[j], acc[i][j]);
        }
    }
    float bj[8];
#pragma unroll
    for (int j = 0; j < 8; j++) bj[j] = b1[bn+tn+j] + b2[bn+tn+j];
#pragma unroll
    for (int i = 0; i < 8; i++) {
        float4 v0, v1;
        v0.x = acc[i][0]+bj[0]; v0.y = acc[i][1]+bj[1]; v0.z = acc[i][2]+bj[2]; v0.w = acc[i][3]+bj[3];
        v1.x = acc[i][4]+bj[4]; v1.y = acc[i][5]+bj[5]; v1.z = acc[i][6]+bj[6]; v1.w = acc[i][7]+bj[7];
        *(float4*)&C[(size_t)(bm+tm+i)*N + bn+tn]     = v0;
        *(float4*)&C[(size_t)(bm+tm+i)*N + bn+tn + 4] = v1;
    }
}

// ---------------- LSTM scan: W_hh register-resident, 4-block groups exchange h via L2 ----------------
// 256 blocks = 64 groups (32 pairs x 2 dirs) x 4 unit-quarter blocks.
// Group partners share blockIdx%8 (same XCD L2, perf heuristic only).
// Block holds W2-slice [256k][256c'] (c' = g*64+ul) in 256 VGPRs/thread.
// Per step: stage h[2][256] from L2, partial-FMA over k-slices into LDS P,
// combine (tid<128: 2 seqs x 64 units) -> activations -> write h slice + flag release.
__global__ __launch_bounds__(256, 1)
void lstm_scan_kernel(const float* __restrict__ Gf, const float* __restrict__ Gb,
                      const float* __restrict__ W2f, const float* __restrict__ W2b,
                      const int* __restrict__ lengths, float* __restrict__ xout,
                      float* __restrict__ h_glob, int* __restrict__ flags) {
    int bid = blockIdx.x;
    int xcd  = bid & 7;
    int role = (bid >> 3) & 3;        // unit-quarter
    int q    = bid >> 5;
    int gid  = xcd * 8 + q;           // 0..63: partners share (xcd,q)
    int uq   = role;
    int pp   = gid >> 1;              // 0..31 batch-pair
    int dir  = gid & 1;
    int b0   = pp * 2;

    const float* G  = dir ? Gb : Gf;
    const float4* W24 = (const float4*)((dir ? W2b : W2f) + (size_t)uq * 65536);
    float* hg = h_glob + (size_t)gid * 512;      // [2][256]
    int* flg  = flags + gid * 4;

    __shared__ float h_lds[2][256];
    __shared__ float P[8][2][256];
    __shared__ float lds_pad[16384];             // force 1 block/CU (>80KB total LDS)

    int tid = threadIdx.x;
    int kg = tid >> 5, cg = tid & 31;            // k-slice 32, col-group 8

    // ---- preload W chunk: rows k = kg*32+kk, float4-cols cg*2+{0,1} (256 VGPRs) ----
    float4 wreg[64];
#pragma unroll
    for (int kk = 0; kk < 32; kk++) {
        wreg[kk*2+0] = W24[(kg*32+kk)*64 + cg*2 + 0];
        wreg[kk*2+1] = W24[(kg*32+kk)*64 + cg*2 + 1];
    }

    int cb = (tid >> 6) & 1, ul = tid & 63;      // combine role (tid<128)
    int len0 = lengths[b0], len1 = lengths[b0+1];
    int mylen = cb ? len1 : len0;
    int ju = uq * 64 + ul;
    float cstate = 0.f;

    ((float*)h_lds)[tid] = 0.f;
    ((float*)h_lds)[256 + tid] = 0.f;
    if (tid == 0 && len0 < 0) lds_pad[0] = 1.f;  // keep pad live (len0 >= 128 at runtime)
    __syncthreads();

    for (int s = 0; s < LSEQ; s++) {
        if (s > 0) {
            if (tid < 4) {
                while (__hip_atomic_load(&flg[tid], __ATOMIC_ACQUIRE, __HIP_MEMORY_SCOPE_AGENT) < s) {}
            }
            __syncthreads();
            if (tid < 128) ((float4*)h_lds)[tid] = ((const float4*)hg)[tid];
            __syncthreads();
        }

        // prefetch G row for combine phase (hidden under FMA phase)
        int t = 0;
        float gp0 = 0.f, gp1 = 0.f, gp2 = 0.f, gp3 = 0.f;
        if (tid < 128) {
            t = dir ? (s < mylen ? mylen - 1 - s : s) : s;
            const float* gr = G + (size_t)(t * BB + b0 + cb) * 1024;
            gp0 = gr[ju]; gp1 = gr[256 + ju]; gp2 = gr[512 + ju]; gp3 = gr[768 + ju];
        }

        // ---- FMA phase: partials over k in [kg*32, kg*32+32), cols cg*8..+7, both seqs ----
        float4 a00 = {0,0,0,0}, a01 = {0,0,0,0}, a10 = {0,0,0,0}, a11 = {0,0,0,0};
        const float4* h40 = (const float4*)&h_lds[0][kg*32];
        const float4* h41 = (const float4*)&h_lds[1][kg*32];
#pragma unroll
        for (int kk4 = 0; kk4 < 8; kk4++) {
            float4 ha = h40[kk4], hb = h41[kk4];
#pragma unroll
            for (int r = 0; r < 4; r++) {
                float va = (&ha.x)[r], vb = (&hb.x)[r];
                float4 w0 = wreg[(kk4*4+r)*2+0];
                float4 w1 = wreg[(kk4*4+r)*2+1];
                a00.x = fmaf(w0.x, va, a00.x); a00.y = fmaf(w0.y, va, a00.y);
                a00.z = fmaf(w0.z, va, a00.z); a00.w = fmaf(w0.w, va, a00.w);
                a01.x = fmaf(w1.x, va, a01.x); a01.y = fmaf(w1.y, va, a01.y);
                a01.z = fmaf(w1.z, va, a01.z); a01.w = fmaf(w1.w, va, a01.w);
                a10.x = fmaf(w0.x, vb, a10.x); a10.y = fmaf(w0.y, vb, a10.y);
                a10.z = fmaf(w0.z, vb, a10.z); a10.w = fmaf(w0.w, vb, a10.w);
                a11.x = fmaf(w1.x, vb, a11.x); a11.y = fmaf(w1.y, vb, a11.y);
                a11.z = fmaf(w1.z, vb, a11.z); a11.w = fmaf(w1.w, vb, a11.w);
            }
        }
        *(float4*)&P[kg][0][cg*8]     = a00;
        *(float4*)&P[kg][0][cg*8 + 4] = a01;
        *(float4*)&P[kg][1][cg*8]     = a10;
        *(float4*)&P[kg][1][cg*8 + 4] = a11;
        __syncthreads();

        // ---- combine: 128 threads = 2 seqs x 64 units ----
        if (tid < 128) {
            float g0 = gp0, g1 = gp1, g2 = gp2, g3 = gp3;
#pragma unroll
            for (int kgi = 0; kgi < 8; kgi++) {
                g0 += P[kgi][cb][ul];
                g1 += P[kgi][cb][64 + ul];
                g2 += P[kgi][cb][128 + ul];
                g3 += P[kgi][cb][192 + ul];
            }
            float iv = 1.f / (1.f + expf(-g0));
            float fv = 1.f / (1.f + expf(-g1));
            float gv = tanhf(g2);
            float ov = 1.f / (1.f + expf(-g3));
            cstate = fv * cstate + iv * gv;
            float h = ov * tanhf(cstate);
            hg[cb * 256 + ju] = h;
            xout[(size_t)(t * BB + b0 + cb) * 512 + dir * 256 + ju] = (s < mylen) ? h : 0.f;
        }
        __syncthreads();   // P-reads done; hg/xout stores drained (vmcnt(0) before barrier)
        if (tid == 0) {
            __threadfence();
            __hip_atomic_store(&flg[role], s + 1, __ATOMIC_RELEASE, __HIP_MEMORY_SCOPE_AGENT);
        }
    }
}

// ---------------- emissions: em[r][n] = x[r]·w_out[n] + b_out[n] ----------------
__global__ __launch_bounds__(256)
void emis_kernel(const float* __restrict__ x, const float* __restrict__ w_out,
                 const float* __restrict__ b_out, float* __restrict__ em) {
    __shared__ float ws_[16][516];
    __shared__ float xs[16][516];
    int tid = threadIdx.x;
    size_t r0 = (size_t)blockIdx.x * 16;
    for (int i4 = tid; i4 < 2048; i4 += 256) {
        int r = i4 >> 7, k4 = (i4 & 127) << 2;
        *(float4*)&ws_[r][k4] = *(const float4*)&w_out[r*512 + k4];
        *(float4*)&xs[r][k4]  = *(const float4*)&x[(r0 + r)*512 + k4];
    }
    __syncthreads();
    int rr = tid >> 4, n = tid & 15;
    const float4* xr = (const float4*)&xs[rr][0];
    const float4* wr = (const float4*)&ws_[n][0];
    float4 s; s.x = s.y = s.z = s.w = 0.f;
#pragma unroll 8
    for (int k = 0; k < 128; k++) {
        float4 a = xr[k], b = wr[k];
        s.x = fmaf(a.x,b.x,s.x); s.y = fmaf(a.y,b.y,s.y);
        s.z = fmaf(a.z,b.z,s.z); s.w = fmaf(a.w,b.w,s.w);
    }
    em[(r0+rr)*16 + n] = s.x+s.y+s.z+s.w + b_out[n];
}

// ---------------- CRF Viterbi decode, one block per batch element ----------------
__global__ __launch_bounds__(64)
void viterbi_kernel(const float* __restrict__ em, const int* __restrict__ tokens,
                    const float* __restrict__ start_trans, const float* __restrict__ end_trans,
                    const float* __restrict__ trans, float* __restrict__ out) {
    __shared__ float em_s[256][16];
    __shared__ float tr_s[16][16];
    __shared__ float sc[16];
    __shared__ unsigned char hist[255][16];
    int b = blockIdx.x, tid = threadIdx.x;
    for (int i = tid; i < 4096; i += 64) {
        int t = i >> 4, n = i & 15;
        em_s[t][n] = em[(size_t)t*1024 + b*16 + n];
    }
    for (int i = tid; i < 256; i += 64) ((float*)tr_s)[i] = trans[i];
    __syncthreads();
    if (tid < 16) sc[tid] = start_trans[tid] + em_s[0][tid];
    __syncthreads();
    for (int t = 1; t < 256; t++) {
        float best = 0.f; int arg = 0;
        if (tid < 16) {
            best = sc[0] + tr_s[0][tid];
#pragma unroll
            for (int i = 1; i < 16; i++) {
                float v = sc[i] + tr_s[i][tid];
                if (v > best) { best = v; arg = i; }   // strict >: first-max, matches argmax
            }
            best += em_s[t][tid];
            hist[t-1][tid] = (unsigned char)arg;
        }
        bool m = tokens[t*64 + b] != 0;
        __syncthreads();
        if (tid < 16 && m) sc[tid] = best;
        __syncthreads();
    }
    if (tid == 0) {
        float best = sc[0] + end_trans[0]; int cur = 0;
        for (int jj = 1; jj < 16; jj++) {
            float v = sc[jj] + end_trans[jj];
            if (v > best) { best = v; cur = jj; }
        }
        out[b] = best;                               // best_score
        float* tags = out + 64;                      // tags [L][B] as float values
        tags[255*64 + b] = (tokens[255*64+b] != 0) ? (float)cur : 0.f;
        for (int t = 254; t >= 0; t--) {
            if (tokens[(t+1)*64 + b] != 0) cur = hist[t][cur];
            tags[t*64 + b] = (tokens[t*64+b] != 0) ? (float)cur : 0.f;
        }
    }
}

extern "C" void kernel_launch(void* const* d_in, const int* in_sizes, int n_in,
                              void* d_out, int out_size, void* d_ws, size_t ws_size,
                              hipStream_t stream) {
    const int*   tokens   = (const int*)d_in[0];
    const int*   lengths  = (const int*)d_in[1];
    const float* emb      = (const float*)d_in[2];
    const float* w_ih_l0f = (const float*)d_in[3];
    const float* w_hh_l0f = (const float*)d_in[4];
    const float* b_ih_l0f = (const float*)d_in[5];
    const float* b_hh_l0f = (const float*)d_in[6];
    const float* w_ih_l0b = (const float*)d_in[7];
    const float* w_hh_l0b = (const float*)d_in[8];
    const float* b_ih_l0b = (const float*)d_in[9];
    const float* b_hh_l0b = (const float*)d_in[10];
    const float* w_ih_l1f = (const float*)d_in[11];
    const float* w_hh_l1f = (const float*)d_in[12];
    const float* b_ih_l1f = (const float*)d_in[13];
    const float* b_hh_l1f = (const float*)d_in[14];
    const float* w_ih_l1b = (const float*)d_in[15];
    const float* w_hh_l1b = (const float*)d_in[16];
    const float* b_ih_l1b = (const float*)d_in[17];
    const float* b_hh_l1b = (const float*)d_in[18];
    const float* w_out    = (const float*)d_in[19];
    const float* b_out    = (const float*)d_in[20];
    const float* start_tr = (const float*)d_in[21];
    const float* end_tr   = (const float*)d_in[22];
    const float* trans    = (const float*)d_in[23];

    // workspace layout (floats)
    float* ws  = (float*)d_ws;
    float* x0  = ws;                       // [16384][256]
    float* x1  = x0 + 4194304;             // [16384][512]
    float* x2  = x1 + 8388608;             // [16384][512]
    float* Gf  = x2 + 8388608;             // [16384][1024]
    float* Gb  = Gf + 16777216;            // [16384][1024]
    float* W2  = Gb + 16777216;            // 4 x [4][256][256] packed W_hh
    float* W2l0f = W2, *W2l0b = W2 + 262144, *W2l1f = W2 + 524288, *W2l1b = W2 + 786432;
    float* h_glob = W2 + 1048576;          // [64][512]
    int*   flags  = (int*)(h_glob + 32768);// 2 x 256 ints
    float* em  = x0;                       // reuse x0 (free after layer-0 GEMMs)

    embed_kernel<<<16384, 64, 0, stream>>>(tokens, emb, x0);
    transpose_whh_kernel<<<dim3(4, 16, 4), 256, 0, stream>>>(w_hh_l0f, w_hh_l0b, w_hh_l1f, w_hh_l1b, W2);
    init_flags_kernel<<<1, 256, 0, stream>>>(flags);

    dim3 gg(128, 8);
    gemm_bias_kernel<<<gg, 256, 0, stream>>>(x0, w_ih_l0f, b_ih_l0f, b_hh_l0f, Gf, 16384, 1024, 256);
    gemm_bias_kernel<<<gg, 256, 0, stream>>>(x0, w_ih_l0b, b_ih_l0b, b_hh_l0b, Gb, 16384, 1024, 256);
    lstm_scan_kernel<<<256, 256, 0, stream>>>(Gf, Gb, W2l0f, W2l0b, lengths, x1, h_glob, flags);

    gemm_bias_kernel<<<gg, 256, 0, stream>>>(x1, w_ih_l1f, b_ih_l1f, b_hh_l1f, Gf, 16384, 1024, 512);
    gemm_bias_kernel<<<gg, 256, 0, stream>>>(x1, w_ih_l1b, b_ih_l1b, b_hh_l1b, Gb, 16384, 1024, 512);
    lstm_scan_kernel<<<256, 256, 0, stream>>>(Gf, Gb, W2l1f, W2l1b, lengths, x2, h_glob, flags + 256);

    emis_kernel<<<1024, 256, 0, stream>>>(x2, w_out, b_out, em);
    viterbi_kernel<<<64, 64, 0, stream>>>(em, tokens, start_tr, end_tr, trans, (float*)d_out);
}

// Round 4
// 3467.952 us; speedup vs baseline: 2.2107x; 2.2107x over previous
//
#include <hip/hip_runtime.h>
#include <hip/hip_bf16.h>
#include <math.h>

#define LSEQ 256
#define BB   64
#define EE   256
#define HH   256

// ---------------- embedding gather: x0[r][e] = emb[tokens[r]][e] ----------------
__global__ __launch_bounds__(64)
void embed_kernel(const int* __restrict__ tokens, const float* __restrict__ emb,
                  float* __restrict__ x0) {
    int r = blockIdx.x;
    int tok = tokens[r];
    const float4* src = (const float4*)(emb + (size_t)tok * EE);
    float4* dst = (float4*)(x0 + (size_t)r * EE);
    dst[threadIdx.x] = src[threadIdx.x];
}

// ---- pack W_hh into W3[ld][ut(16)][k(256)][c(64)], c = g*16+ul, src w[(g*256+ut*16+ul)][k] ----
__global__ __launch_bounds__(256)
void pack_w3_kernel(const float* __restrict__ w0, const float* __restrict__ w1,
                    const float* __restrict__ w2, const float* __restrict__ w3,
                    float* __restrict__ W3) {
    __shared__ float t[16][65];
    const float* w = blockIdx.z == 0 ? w0 : blockIdx.z == 1 ? w1 : blockIdx.z == 2 ? w2 : w3;
    float* out = W3 + (size_t)blockIdx.z * 262144;
    int ut = blockIdx.y;
    int g = blockIdx.x >> 2, kt = blockIdx.x & 3;
    int k0 = kt * 64, tid = threadIdx.x;
    for (int e = tid; e < 1024; e += 256) {
        int ul = e >> 6, kl = e & 63;
        t[ul][kl] = w[(size_t)(g * 256 + ut * 16 + ul) * 256 + k0 + kl];
    }
    __syncthreads();
    for (int e = tid; e < 1024; e += 256) {
        int kl = e >> 4, ul = e & 15;
        out[(size_t)(ut * 256 + k0 + kl) * 64 + g * 16 + ul] = t[ul][kl];
    }
}

// ---------------- zero the scan sync counters (runs every launch, graph-safe) ----------------
__global__ __launch_bounds__(256)
void init_cnt_kernel(int* __restrict__ cnt) {
    cnt[blockIdx.x * 256 + threadIdx.x] = 0;
}

// ---------------- C[M,N] = A[M,K] @ W[N,K]^T + b1[N] + b2[N] ----------------
__global__ __launch_bounds__(256)
void gemm_bias_kernel(const float* __restrict__ A, const float* __restrict__ W,
                      const float* __restrict__ b1, const float* __restrict__ b2,
                      float* __restrict__ C, int M, int N, int K) {
    const int BK = 16;
    __shared__ float As[BK][128];
    __shared__ float Bs[BK][128];
    int tid = threadIdx.x;
    int bm = blockIdx.x * 128;
    int bn = blockIdx.y * 128;
    int tm = (tid >> 4) << 3;
    int tn = (tid & 15) << 3;
    int lr = tid >> 1;
    int lc = (tid & 1) << 3;
    const float* Ap = A + (size_t)(bm + lr) * K + lc;
    const float* Wpt = W + (size_t)(bn + lr) * K + lc;
    float acc[8][8];
#pragma unroll
    for (int i = 0; i < 8; i++)
#pragma unroll
        for (int j = 0; j < 8; j++) acc[i][j] = 0.f;

    for (int k0 = 0; k0 < K; k0 += BK) {
        float4 a0 = *(const float4*)(Ap + k0);
        float4 a1 = *(const float4*)(Ap + k0 + 4);
        float4 w0 = *(const float4*)(Wpt + k0);
        float4 w1 = *(const float4*)(Wpt + k0 + 4);
        __syncthreads();
        As[lc+0][lr]=a0.x; As[lc+1][lr]=a0.y; As[lc+2][lr]=a0.z; As[lc+3][lr]=a0.w;
        As[lc+4][lr]=a1.x; As[lc+5][lr]=a1.y; As[lc+6][lr]=a1.z; As[lc+7][lr]=a1.w;
        Bs[lc+0][lr]=w0.x; Bs[lc+1][lr]=w0.y; Bs[lc+2][lr]=w0.z; Bs[lc+3][lr]=w0.w;
        Bs[lc+4][lr]=w1.x; Bs[lc+5][lr]=w1.y; Bs[lc+6][lr]=w1.z; Bs[lc+7][lr]=w1.w;
        __syncthreads();
#pragma unroll
        for (int k = 0; k < BK; k++) {
            float av[8], bv[8];
            *(float4*)&av[0] = *(const float4*)&As[k][tm];
            *(float4*)&av[4] = *(const float4*)&As[k][tm+4];
            *(float4*)&bv[0] = *(const float4*)&Bs[k][tn];
            *(float4*)&bv[4] = *(const float4*)&Bs[k][tn+4];
#pragma unroll
            for (int i = 0; i < 8; i++)
#pragma unroll
                for (int j = 0; j < 8; j++) acc[i][j] = fmaf(av[i], bv[j], acc[i][j]);
        }
    }
    float bj[8];
#pragma unroll
    for (int j = 0; j < 8; j++) bj[j] = b1[bn+tn+j] + b2[bn+tn+j];
#pragma unroll
    for (int i = 0; i < 8; i++) {
        float4 v0, v1;
        v0.x = acc[i][0]+bj[0]; v0.y = acc[i][1]+bj[1]; v0.z = acc[i][2]+bj[2]; v0.w = acc[i][3]+bj[3];
        v1.x = acc[i][4]+bj[4]; v1.y = acc[i][5]+bj[5]; v1.z = acc[i][6]+bj[6]; v1.w = acc[i][7]+bj[7];
        *(float4*)&C[(size_t)(bm+tm+i)*N + bn+tn]     = v0;
        *(float4*)&C[(size_t)(bm+tm+i)*N + bn+tn + 4] = v1;
    }
}

// ---------------- LSTM scan: unit-split 16 blocks/domain, coherent-point exchange ----------------
// 128 blocks = 2 dir x 4 batch-tiles(16) x 16 unit-tiles(16 units = 64 gate-cols).
// W-slice [256k][64c] in VGPRs (64/thread). Per step: FMA partials (kg=8 k-split) -> LDS P
// (XOR-swizzled) -> combine+activations -> publish h via atomicExch -> count via atomicAdd.
// Poll = atomicAdd(p,0) (RMW, coherent); consume h via relaxed agent atomic loads (bypass).
// NO fences / NO acquire/release => no buffer_wbl2 / buffer_inv storms (round-3 lesson).
__global__ __launch_bounds__(256, 1)
void lstm_scan_kernel(const float* __restrict__ Gf, const float* __restrict__ Gb,
                      const float* __restrict__ W3f, const float* __restrict__ W3b,
                      const int* __restrict__ lengths, float* __restrict__ xout,
                      float* __restrict__ hg, int* __restrict__ cnt) {
    const int bid = blockIdx.x;
    const int dir = bid >> 6, bt = (bid >> 4) & 3, ut = bid & 15;
    const int dom = dir * 4 + bt;
    const float* __restrict__ G = dir ? Gb : Gf;
    const float* __restrict__ W3 = (dir ? W3b : W3f) + (size_t)ut * 16384;
    float* hgD = hg + (size_t)dom * 8192;          // [2 parity][16 b][256 u]
    int* cntD = cnt + (size_t)dom * 8192;          // [256 steps][32-int pad]

    __shared__ float hs[4096];                     // h(s-1): [16 b][256 u]
    __shared__ float P[8192];                      // [8 kg][16 b][64 c], xor-swizzled

    const int tid = threadIdx.x;
    const int kg = tid >> 5;                       // 0..7  : k-slice of 32
    const int cw = tid & 31;                       // 0..31 : col pair c = 2cw, 2cw+1
    const int cb = tid >> 4;                       // 0..15 : combine batch row
    const int cu = tid & 15;                       // 0..15 : combine unit-local
    const int bg = bt * 16 + cb;
    const int ug = ut * 16 + cu;
    const int mylen = lengths[bg];

    // W registers: wreg[kk] = W3[kg*32+kk][2cw .. 2cw+1]
    float2 wreg[32];
#pragma unroll
    for (int kk = 0; kk < 32; kk++)
        wreg[kk] = *(const float2*)&W3[(size_t)(kg * 32 + kk) * 64 + cw * 2];

#pragma unroll
    for (int i = 0; i < 4; i++)
        *(float4*)&hs[(tid + 256 * i) * 4] = make_float4(0.f, 0.f, 0.f, 0.f);

    float cstate = 0.f;
    int tcur = dir ? (mylen - 1) : 0;
    {
        const float* gr = G + ((size_t)tcur * BB + bg) * 1024 + ug;
        // gp0..3 prefetched gate biases+inputs for current step
    }
    const float* gr0 = G + ((size_t)tcur * BB + bg) * 1024 + ug;
    float gp0 = gr0[0], gp1 = gr0[256], gp2 = gr0[512], gp3 = gr0[768];
    __syncthreads();

    for (int s = 0; s < LSEQ; s++) {
        if (s > 0) {
            if (tid == 0) {
                int* cp = &cntD[(s - 1) * 32];
                while (atomicAdd(cp, 0) < 16) __builtin_amdgcn_s_sleep(8);
            }
            __syncthreads();
            const unsigned long long* src =
                (const unsigned long long*)(hgD + ((s - 1) & 1) * 4096);
            unsigned long long v[8];
#pragma unroll
            for (int i = 0; i < 8; i++)
                v[i] = __hip_atomic_load(src + tid + 256 * i, __ATOMIC_RELAXED,
                                         __HIP_MEMORY_SCOPE_AGENT);
#pragma unroll
            for (int i = 0; i < 8; i++)
                *(unsigned long long*)&hs[(tid + 256 * i) * 2] = v[i];
            __syncthreads();
        }

        // ---- FMA phase: acc[b] (2 cols) partial over k in [kg*32, kg*32+32) ----
        float2 acc[16];
        const float4* h4 = (const float4*)hs;
#pragma unroll
        for (int b = 0; b < 16; b++) {
            float2 a = make_float2(0.f, 0.f);
            int hbase = b * 64 + kg * 8;
#pragma unroll
            for (int q = 0; q < 8; q++) {
                float4 hv = h4[hbase + q];
                a.x = fmaf(wreg[q*4+0].x, hv.x, a.x); a.y = fmaf(wreg[q*4+0].y, hv.x, a.y);
                a.x = fmaf(wreg[q*4+1].x, hv.y, a.x); a.y = fmaf(wreg[q*4+1].y, hv.y, a.y);
                a.x = fmaf(wreg[q*4+2].x, hv.z, a.x); a.y = fmaf(wreg[q*4+2].y, hv.z, a.y);
                a.x = fmaf(wreg[q*4+3].x, hv.w, a.x); a.y = fmaf(wreg[q*4+3].y, hv.w, a.y);
            }
            acc[b] = a;
        }
        const int wofs = (cw * 2) ^ (kg * 2);      // xor-swizzle: conflict-free banks
#pragma unroll
        for (int b = 0; b < 16; b++)
            *(float2*)&P[kg * 1024 + b * 64 + wofs] = acc[b];
        __syncthreads();

        // ---- combine: thread (cb, cu) sums 8 kg-partials for its 4 gates ----
        float g0 = gp0, g1 = gp1, g2 = gp2, g3 = gp3;
#pragma unroll
        for (int k2 = 0; k2 < 8; k2++) {
            int base = k2 * 1024 + cb * 64;
            int x = k2 * 2;
            g0 += P[base + ((cu)      ^ x)];
            g1 += P[base + ((16 + cu) ^ x)];
            g2 += P[base + ((32 + cu) ^ x)];
            g3 += P[base + ((48 + cu) ^ x)];
        }
        float iv = 1.f / (1.f + expf(-g0));
        float fv = 1.f / (1.f + expf(-g1));
        float gv = tanhf(g2);
        float ov = 1.f / (1.f + expf(-g3));
        cstate = fv * cstate + iv * gv;
        float h = ov * tanhf(cstate);

        atomicExch(&hgD[(s & 1) * 4096 + cb * 256 + ug], h);       // publish (coherent RMW)
        xout[(size_t)(tcur * BB + bg) * 512 + dir * 256 + ug] = (s < mylen) ? h : 0.f;

        asm volatile("s_waitcnt vmcnt(0)" ::: "memory");
        __syncthreads();                                            // all publishes drained
        if (tid == 0) atomicAdd(&cntD[s * 32], 1);                  // arrival

        if (s < 255) {                                              // G prefetch under poll
            int s2 = s + 1;
            tcur = dir ? (s2 < mylen ? mylen - 1 - s2 : s2) : s2;
            const float* gr = G + ((size_t)tcur * BB + bg) * 1024 + ug;
            gp0 = gr[0]; gp1 = gr[256]; gp2 = gr[512]; gp3 = gr[768];
        }
    }
}

// ---------------- emissions: em[r][n] = x[r]·w_out[n] + b_out[n] ----------------
__global__ __launch_bounds__(256)
void emis_kernel(const float* __restrict__ x, const float* __restrict__ w_out,
                 const float* __restrict__ b_out, float* __restrict__ em) {
    __shared__ float ws_[16][516];
    __shared__ float xs[16][516];
    int tid = threadIdx.x;
    size_t r0 = (size_t)blockIdx.x * 16;
    for (int i4 = tid; i4 < 2048; i4 += 256) {
        int r = i4 >> 7, k4 = (i4 & 127) << 2;
        *(float4*)&ws_[r][k4] = *(const float4*)&w_out[r*512 + k4];
        *(float4*)&xs[r][k4]  = *(const float4*)&x[(r0 + r)*512 + k4];
    }
    __syncthreads();
    int rr = tid >> 4, n = tid & 15;
    const float4* xr = (const float4*)&xs[rr][0];
    const float4* wr = (const float4*)&ws_[n][0];
    float4 s; s.x = s.y = s.z = s.w = 0.f;
#pragma unroll 8
    for (int k = 0; k < 128; k++) {
        float4 a = xr[k], b = wr[k];
        s.x = fmaf(a.x,b.x,s.x); s.y = fmaf(a.y,b.y,s.y);
        s.z = fmaf(a.z,b.z,s.z); s.w = fmaf(a.w,b.w,s.w);
    }
    em[(r0+rr)*16 + n] = s.x+s.y+s.z+s.w + b_out[n];
}

// ---------------- CRF Viterbi decode, one block per batch element ----------------
__global__ __launch_bounds__(64)
void viterbi_kernel(const float* __restrict__ em, const int* __restrict__ tokens,
                    const float* __restrict__ start_trans, const float* __restrict__ end_trans,
                    const float* __restrict__ trans, float* __restrict__ out) {
    __shared__ float em_s[256][16];
    __shared__ float tr_s[16][16];
    __shared__ float sc[16];
    __shared__ unsigned char hist[255][16];
    int b = blockIdx.x, tid = threadIdx.x;
    for (int i = tid; i < 4096; i += 64) {
        int t = i >> 4, n = i & 15;
        em_s[t][n] = em[(size_t)t*1024 + b*16 + n];
    }
    for (int i = tid; i < 256; i += 64) ((float*)tr_s)[i] = trans[i];
    __syncthreads();
    if (tid < 16) sc[tid] = start_trans[tid] + em_s[0][tid];
    __syncthreads();
    for (int t = 1; t < 256; t++) {
        float best = 0.f; int arg = 0;
        if (tid < 16) {
            best = sc[0] + tr_s[0][tid];
#pragma unroll
            for (int i = 1; i < 16; i++) {
                float v = sc[i] + tr_s[i][tid];
                if (v > best) { best = v; arg = i; }
            }
            best += em_s[t][tid];
            hist[t-1][tid] = (unsigned char)arg;
        }
        bool m = tokens[t*64 + b] != 0;
        __syncthreads();
        if (tid < 16 && m) sc[tid] = best;
        __syncthreads();
    }
    if (tid == 0) {
        float best = sc[0] + end_trans[0]; int cur = 0;
        for (int jj = 1; jj < 16; jj++) {
            float v = sc[jj] + end_trans[jj];
            if (v > best) { best = v; cur = jj; }
        }
        out[b] = best;
        float* tags = out + 64;
        tags[255*64 + b] = (tokens[255*64+b] != 0) ? (float)cur : 0.f;
        for (int t = 254; t >= 0; t--) {
            if (tokens[(t+1)*64 + b] != 0) cur = hist[t][cur];
            tags[t*64 + b] = (tokens[t*64+b] != 0) ? (float)cur : 0.f;
        }
    }
}

extern "C" void kernel_launch(void* const* d_in, const int* in_sizes, int n_in,
                              void* d_out, int out_size, void* d_ws, size_t ws_size,
                              hipStream_t stream) {
    const int*   tokens   = (const int*)d_in[0];
    const int*   lengths  = (const int*)d_in[1];
    const float* emb      = (const float*)d_in[2];
    const float* w_ih_l0f = (const float*)d_in[3];
    const float* w_hh_l0f = (const float*)d_in[4];
    const float* b_ih_l0f = (const float*)d_in[5];
    const float* b_hh_l0f = (const float*)d_in[6];
    const float* w_ih_l0b = (const float*)d_in[7];
    const float* w_hh_l0b = (const float*)d_in[8];
    const float* b_ih_l0b = (const float*)d_in[9];
    const float* b_hh_l0b = (const float*)d_in[10];
    const float* w_ih_l1f = (const float*)d_in[11];
    const float* w_hh_l1f = (const float*)d_in[12];
    const float* b_ih_l1f = (const float*)d_in[13];
    const float* b_hh_l1f = (const float*)d_in[14];
    const float* w_ih_l1b = (const float*)d_in[15];
    const float* w_hh_l1b = (const float*)d_in[16];
    const float* b_ih_l1b = (const float*)d_in[17];
    const float* b_hh_l1b = (const float*)d_in[18];
    const float* w_out    = (const float*)d_in[19];
    const float* b_out    = (const float*)d_in[20];
    const float* start_tr = (const float*)d_in[21];
    const float* end_tr   = (const float*)d_in[22];
    const float* trans    = (const float*)d_in[23];

    // workspace layout (floats) — identical total footprint to round 2 (fits ws)
    float* ws  = (float*)d_ws;
    float* x0  = ws;                       // [16384][256]  (later: em + hg + cnt overlays)
    float* x1  = x0 + 4194304;             // [16384][512]
    float* x2  = x1 + 8388608;             // [16384][512]
    float* Gf  = x2 + 8388608;             // [16384][1024]
    float* Gb  = Gf + 16777216;            // [16384][1024]
    float* W3  = Gb + 16777216;            // 4 x [16][256][64] packed W_hh
    float* W3l0f = W3, *W3l0b = W3 + 262144, *W3l1f = W3 + 524288, *W3l1b = W3 + 786432;
    float* em  = x0;                       // [16384][16], reuse x0 after layer-0 GEMMs
    float* hg  = x0 + 1048576;             // [8 dom][2 par][16][256] = 65536 floats (x0 overlay)
    int*   cnt = (int*)(x0 + 1179648);     // 2 layers x [8 dom][256 steps][32] = 131072 ints

    embed_kernel<<<16384, 64, 0, stream>>>(tokens, emb, x0);
    pack_w3_kernel<<<dim3(16, 16, 4), 256, 0, stream>>>(w_hh_l0f, w_hh_l0b, w_hh_l1f, w_hh_l1b, W3);

    dim3 gg(128, 8);
    gemm_bias_kernel<<<gg, 256, 0, stream>>>(x0, w_ih_l0f, b_ih_l0f, b_hh_l0f, Gf, 16384, 1024, 256);
    gemm_bias_kernel<<<gg, 256, 0, stream>>>(x0, w_ih_l0b, b_ih_l0b, b_hh_l0b, Gb, 16384, 1024, 256);
    init_cnt_kernel<<<512, 256, 0, stream>>>(cnt);   // after x0 consumed, before scan1
    lstm_scan_kernel<<<128, 256, 0, stream>>>(Gf, Gb, W3l0f, W3l0b, lengths, x1, hg, cnt);

    gemm_bias_kernel<<<gg, 256, 0, stream>>>(x1, w_ih_l1f, b_ih_l1f, b_hh_l1f, Gf, 16384, 1024, 512);
    gemm_bias_kernel<<<gg, 256, 0, stream>>>(x1, w_ih_l1b, b_ih_l1b, b_hh_l1b, Gb, 16384, 1024, 512);
    lstm_scan_kernel<<<128, 256, 0, stream>>>(Gf, Gb, W3l1f, W3l1b, lengths, x2, hg, cnt + 65536);

    emis_kernel<<<1024, 256, 0, stream>>>(x2, w_out, b_out, em);
    viterbi_kernel<<<64, 64, 0, stream>>>(em, tokens, start_tr, end_tr, trans, (float*)d_out);
}

// Round 5
// 2365.309 us; speedup vs baseline: 3.2413x; 1.4662x over previous
//
#include <hip/hip_runtime.h>
#include <hip/hip_bf16.h>
#include <math.h>

#define LSEQ 256
#define BB   64
#define EE   256
#define HH   256

// ---------------- embedding gather: x0[r][e] = emb[tokens[r]][e] ----------------
__global__ __launch_bounds__(64)
void embed_kernel(const int* __restrict__ tokens, const float* __restrict__ emb,
                  float* __restrict__ x0) {
    int r = blockIdx.x;
    int tok = tokens[r];
    const float4* src = (const float4*)(emb + (size_t)tok * EE);
    float4* dst = (float4*)(x0 + (size_t)r * EE);
    dst[threadIdx.x] = src[threadIdx.x];
}

// ---- pack W_hh into W3[ld][ut(16)][k(256)][c(64)], c = g*16+ul, src w[(g*256+ut*16+ul)][k] ----
__global__ __launch_bounds__(256)
void pack_w3_kernel(const float* __restrict__ w0, const float* __restrict__ w1,
                    const float* __restrict__ w2, const float* __restrict__ w3,
                    float* __restrict__ W3) {
    __shared__ float t[16][65];
    const float* w = blockIdx.z == 0 ? w0 : blockIdx.z == 1 ? w1 : blockIdx.z == 2 ? w2 : w3;
    float* out = W3 + (size_t)blockIdx.z * 262144;
    int ut = blockIdx.y;
    int g = blockIdx.x >> 2, kt = blockIdx.x & 3;
    int k0 = kt * 64, tid = threadIdx.x;
    for (int e = tid; e < 1024; e += 256) {
        int ul = e >> 6, kl = e & 63;
        t[ul][kl] = w[(size_t)(g * 256 + ut * 16 + ul) * 256 + k0 + kl];
    }
    __syncthreads();
    for (int e = tid; e < 1024; e += 256) {
        int kl = e >> 4, ul = e & 15;
        out[(size_t)(ut * 256 + k0 + kl) * 64 + g * 16 + ul] = t[ul][kl];
    }
}

// ---------------- zero the scan sync counters (runs every launch, graph-safe) ----------------
__global__ __launch_bounds__(256)
void init_cnt_kernel(int* __restrict__ cnt) {
    cnt[blockIdx.x * 256 + threadIdx.x] = 0;
}

// ---------------- C[M,N] = A[M,K] @ W[N,K]^T + b1[N] + b2[N] ----------------
__global__ __launch_bounds__(256)
void gemm_bias_kernel(const float* __restrict__ A, const float* __restrict__ W,
                      const float* __restrict__ b1, const float* __restrict__ b2,
                      float* __restrict__ C, int M, int N, int K) {
    const int BK = 16;
    __shared__ float As[BK][128];
    __shared__ float Bs[BK][128];
    int tid = threadIdx.x;
    int bm = blockIdx.x * 128;
    int bn = blockIdx.y * 128;
    int tm = (tid >> 4) << 3;
    int tn = (tid & 15) << 3;
    int lr = tid >> 1;
    int lc = (tid & 1) << 3;
    const float* Ap = A + (size_t)(bm + lr) * K + lc;
    const float* Wpt = W + (size_t)(bn + lr) * K + lc;
    float acc[8][8];
#pragma unroll
    for (int i = 0; i < 8; i++)
#pragma unroll
        for (int j = 0; j < 8; j++) acc[i][j] = 0.f;

    for (int k0 = 0; k0 < K; k0 += BK) {
        float4 a0 = *(const float4*)(Ap + k0);
        float4 a1 = *(const float4*)(Ap + k0 + 4);
        float4 w0 = *(const float4*)(Wpt + k0);
        float4 w1 = *(const float4*)(Wpt + k0 + 4);
        __syncthreads();
        As[lc+0][lr]=a0.x; As[lc+1][lr]=a0.y; As[lc+2][lr]=a0.z; As[lc+3][lr]=a0.w;
        As[lc+4][lr]=a1.x; As[lc+5][lr]=a1.y; As[lc+6][lr]=a1.z; As[lc+7][lr]=a1.w;
        Bs[lc+0][lr]=w0.x; Bs[lc+1][lr]=w0.y; Bs[lc+2][lr]=w0.z; Bs[lc+3][lr]=w0.w;
        Bs[lc+4][lr]=w1.x; Bs[lc+5][lr]=w1.y; Bs[lc+6][lr]=w1.z; Bs[lc+7][lr]=w1.w;
        __syncthreads();
#pragma unroll
        for (int k = 0; k < BK; k++) {
            float av[8], bv[8];
            *(float4*)&av[0] = *(const float4*)&As[k][tm];
            *(float4*)&av[4] = *(const float4*)&As[k][tm+4];
            *(float4*)&bv[0] = *(const float4*)&Bs[k][tn];
            *(float4*)&bv[4] = *(const float4*)&Bs[k][tn+4];
#pragma unroll
            for (int i = 0; i < 8; i++)
#pragma unroll
                for (int j = 0; j < 8; j++) acc[i][j] = fmaf(av[i], bv[j], acc[i][j]);
        }
    }
    float bj[8];
#pragma unroll
    for (int j = 0; j < 8; j++) bj[j] = b1[bn+tn+j] + b2[bn+tn+j];
#pragma unroll
    for (int i = 0; i < 8; i++) {
        float4 v0, v1;
        v0.x = acc[i][0]+bj[0]; v0.y = acc[i][1]+bj[1]; v0.z = acc[i][2]+bj[2]; v0.w = acc[i][3]+bj[3];
        v1.x = acc[i][4]+bj[4]; v1.y = acc[i][5]+bj[5]; v1.z = acc[i][6]+bj[6]; v1.w = acc[i][7]+bj[7];
        *(float4*)&C[(size_t)(bm+tm+i)*N + bn+tn]     = v0;
        *(float4*)&C[(size_t)(bm+tm+i)*N + bn+tn + 4] = v1;
    }
}

// ---------------- LSTM scan: 16 XCD-local domains x 16 unit-blocks ----------------
// 256 blocks; dom = bid&15 (all 16 blocks of a dom share bid%8 -> same XCD under
// round-robin dispatch), ut = bid>>4. dom -> dir = dom&1, batch-tile bt = dom>>1 (8 seqs).
// W-slice [256k][64c] in VGPRs (64/thread). Poll = relaxed agent atomic LOAD (no RMW
// contention; coherence of this path proven in round 4). Publish h via atomicExch;
// arrival via one atomicAdd per block after vmcnt(0)+barrier. No fences anywhere.
__global__ __launch_bounds__(256, 1)
void lstm_scan_kernel(const float* __restrict__ Gf, const float* __restrict__ Gb,
                      const float* __restrict__ W3f, const float* __restrict__ W3b,
                      const int* __restrict__ lengths, float* __restrict__ xout,
                      float* __restrict__ hg, int* __restrict__ cnt) {
    const int bid = blockIdx.x;
    const int dom = bid & 15;
    const int ut  = bid >> 4;
    const int dir = dom & 1;
    const int bt  = dom >> 1;                      // 0..7, 8 sequences each
    const float* __restrict__ G = dir ? Gb : Gf;
    const float* __restrict__ W3 = (dir ? W3b : W3f) + (size_t)ut * 16384;
    float* hgD = hg + (size_t)dom * 4096;          // [2 parity][8 b][256 u]
    int* cntD = cnt + (size_t)dom * 8192;          // [256 steps][32-int pad]

    __shared__ float hs[2048];                     // h(s-1): [8 b][256 u]
    __shared__ float P[4096];                      // [8 kg][8 b][64 c], xor-swizzled
    __shared__ float lds_pad[16384];               // force 1 block/CU

    const int tid = threadIdx.x;
    const int kg = tid >> 5;                       // 0..7  : k-slice of 32
    const int cw = tid & 31;                       // 0..31 : col pair c = 2cw, 2cw+1
    const int cb = (tid >> 4) & 7;                 // combine batch row (tid<128)
    const int cu = tid & 15;                       // combine unit-local
    const int bg = bt * 8 + cb;
    const int ug = ut * 16 + cu;
    const int mylen = lengths[bg];

    // W registers: wreg[kk] = W3[kg*32+kk][2cw .. 2cw+1]
    float2 wreg[32];
#pragma unroll
    for (int kk = 0; kk < 32; kk++)
        wreg[kk] = *(const float2*)&W3[(size_t)(kg * 32 + kk) * 64 + cw * 2];

#pragma unroll
    for (int i = 0; i < 2; i++)
        *(float4*)&hs[(tid + 256 * i) * 4] = make_float4(0.f, 0.f, 0.f, 0.f);
    if (tid == 0 && mylen < 0) lds_pad[0] = 1.f;   // keep pad live (mylen >= 128 always)

    float cstate = 0.f;
    int tcur = dir ? (mylen - 1) : 0;
    const float* gr0 = G + ((size_t)tcur * BB + bg) * 1024 + ug;
    float gp0 = gr0[0], gp1 = gr0[256], gp2 = gr0[512], gp3 = gr0[768];
    __syncthreads();

    for (int s = 0; s < LSEQ; s++) {
        if (s > 0) {
            if (tid == 0) {
                const int* cp = &cntD[(s - 1) * 32];
                while (__hip_atomic_load(cp, __ATOMIC_RELAXED, __HIP_MEMORY_SCOPE_AGENT) < 16)
                    __builtin_amdgcn_s_sleep(1);
            }
            __syncthreads();
            const unsigned long long* src =
                (const unsigned long long*)(hgD + ((s - 1) & 1) * 2048);
            unsigned long long v[4];
#pragma unroll
            for (int i = 0; i < 4; i++)
                v[i] = __hip_atomic_load(src + tid + 256 * i, __ATOMIC_RELAXED,
                                         __HIP_MEMORY_SCOPE_AGENT);
#pragma unroll
            for (int i = 0; i < 4; i++)
                *(unsigned long long*)&hs[(tid + 256 * i) * 2] = v[i];
            __syncthreads();
        }

        // ---- FMA phase: acc[b] (2 cols) partial over k in [kg*32, kg*32+32) ----
        float2 acc[8];
        const float4* h4 = (const float4*)hs;
#pragma unroll
        for (int b = 0; b < 8; b++) {
            float2 a = make_float2(0.f, 0.f);
            int hbase = b * 64 + kg * 8;
#pragma unroll
            for (int q = 0; q < 8; q++) {
                float4 hv = h4[hbase + q];
                a.x = fmaf(wreg[q*4+0].x, hv.x, a.x); a.y = fmaf(wreg[q*4+0].y, hv.x, a.y);
                a.x = fmaf(wreg[q*4+1].x, hv.y, a.x); a.y = fmaf(wreg[q*4+1].y, hv.y, a.y);
                a.x = fmaf(wreg[q*4+2].x, hv.z, a.x); a.y = fmaf(wreg[q*4+2].y, hv.z, a.y);
                a.x = fmaf(wreg[q*4+3].x, hv.w, a.x); a.y = fmaf(wreg[q*4+3].y, hv.w, a.y);
            }
            acc[b] = a;
        }
        const int wofs = (cw * 2) ^ (kg * 2);
#pragma unroll
        for (int b = 0; b < 8; b++)
            *(float2*)&P[kg * 512 + b * 64 + wofs] = acc[b];
        __syncthreads();

        float h = 0.f;
        if (tid < 128) {
            // ---- combine: thread (cb, cu) sums 8 kg-partials for its 4 gates ----
            float g0 = gp0, g1 = gp1, g2 = gp2, g3 = gp3;
#pragma unroll
            for (int k2 = 0; k2 < 8; k2++) {
                int base = k2 * 512 + cb * 64;
                int x = k2 * 2;
                g0 += P[base + ((cu)      ^ x)];
                g1 += P[base + ((16 + cu) ^ x)];
                g2 += P[base + ((32 + cu) ^ x)];
                g3 += P[base + ((48 + cu) ^ x)];
            }
            float iv = 1.f / (1.f + expf(-g0));
            float fv = 1.f / (1.f + expf(-g1));
            float gv = tanhf(g2);
            float ov = 1.f / (1.f + expf(-g3));
            cstate = fv * cstate + iv * gv;
            h = ov * tanhf(cstate);
            atomicExch(&hgD[(s & 1) * 2048 + cb * 256 + ug], h);   // publish (coherent RMW)
        }
        asm volatile("s_waitcnt vmcnt(0)" ::: "memory");
        __syncthreads();                                            // all publishes drained
        if (tid == 0) atomicAdd(&cntD[s * 32], 1);                  // arrival

        if (tid < 128) {
            xout[(size_t)(tcur * BB + bg) * 512 + dir * 256 + ug] = (s < mylen) ? h : 0.f;
            if (s < 255) {                                          // G prefetch under poll
                int s2 = s + 1;
                tcur = dir ? (s2 < mylen ? mylen - 1 - s2 : s2) : s2;
                const float* gr = G + ((size_t)tcur * BB + bg) * 1024 + ug;
                gp0 = gr[0]; gp1 = gr[256]; gp2 = gr[512]; gp3 = gr[768];
            }
        }
    }
}

// ---------------- emissions: em[r][n] = x[r]·w_out[n] + b_out[n] ----------------
__global__ __launch_bounds__(256)
void emis_kernel(const float* __restrict__ x, const float* __restrict__ w_out,
                 const float* __restrict__ b_out, float* __restrict__ em) {
    __shared__ float ws_[16][516];
    __shared__ float xs[16][516];
    int tid = threadIdx.x;
    size_t r0 = (size_t)blockIdx.x * 16;
    for (int i4 = tid; i4 < 2048; i4 += 256) {
        int r = i4 >> 7, k4 = (i4 & 127) << 2;
        *(float4*)&ws_[r][k4] = *(const float4*)&w_out[r*512 + k4];
        *(float4*)&xs[r][k4]  = *(const float4*)&x[(r0 + r)*512 + k4];
    }
    __syncthreads();
    int rr = tid >> 4, n = tid & 15;
    const float4* xr = (const float4*)&xs[rr][0];
    const float4* wr = (const float4*)&ws_[n][0];
    float4 s; s.x = s.y = s.z = s.w = 0.f;
#pragma unroll 8
    for (int k = 0; k < 128; k++) {
        float4 a = xr[k], b = wr[k];
        s.x = fmaf(a.x,b.x,s.x); s.y = fmaf(a.y,b.y,s.y);
        s.z = fmaf(a.z,b.z,s.z); s.w = fmaf(a.w,b.w,s.w);
    }
    em[(r0+rr)*16 + n] = s.x+s.y+s.z+s.w + b_out[n];
}

// ---------------- CRF Viterbi decode, one block per batch element ----------------
__global__ __launch_bounds__(64)
void viterbi_kernel(const float* __restrict__ em, const int* __restrict__ tokens,
                    const float* __restrict__ start_trans, const float* __restrict__ end_trans,
                    const float* __restrict__ trans, float* __restrict__ out) {
    __shared__ float em_s[256][16];
    __shared__ float tr_s[16][16];
    __shared__ float sc[16];
    __shared__ unsigned char hist[255][16];
    int b = blockIdx.x, tid = threadIdx.x;
    for (int i = tid; i < 4096; i += 64) {
        int t = i >> 4, n = i & 15;
        em_s[t][n] = em[(size_t)t*1024 + b*16 + n];
    }
    for (int i = tid; i < 256; i += 64) ((float*)tr_s)[i] = trans[i];
    __syncthreads();
    if (tid < 16) sc[tid] = start_trans[tid] + em_s[0][tid];
    __syncthreads();
    for (int t = 1; t < 256; t++) {
        float best = 0.f; int arg = 0;
        if (tid < 16) {
            best = sc[0] + tr_s[0][tid];
#pragma unroll
            for (int i = 1; i < 16; i++) {
                float v = sc[i] + tr_s[i][tid];
                if (v > best) { best = v; arg = i; }
            }
            best += em_s[t][tid];
            hist[t-1][tid] = (unsigned char)arg;
        }
        bool m = tokens[t*64 + b] != 0;
        __syncthreads();
        if (tid < 16 && m) sc[tid] = best;
        __syncthreads();
    }
    if (tid == 0) {
        float best = sc[0] + end_trans[0]; int cur = 0;
        for (int jj = 1; jj < 16; jj++) {
            float v = sc[jj] + end_trans[jj];
            if (v > best) { best = v; cur = jj; }
        }
        out[b] = best;
        float* tags = out + 64;
        tags[255*64 + b] = (tokens[255*64+b] != 0) ? (float)cur : 0.f;
        for (int t = 254; t >= 0; t--) {
            if (tokens[(t+1)*64 + b] != 0) cur = hist[t][cur];
            tags[t*64 + b] = (tokens[t*64+b] != 0) ? (float)cur : 0.f;
        }
    }
}

extern "C" void kernel_launch(void* const* d_in, const int* in_sizes, int n_in,
                              void* d_out, int out_size, void* d_ws, size_t ws_size,
                              hipStream_t stream) {
    const int*   tokens   = (const int*)d_in[0];
    const int*   lengths  = (const int*)d_in[1];
    const float* emb      = (const float*)d_in[2];
    const float* w_ih_l0f = (const float*)d_in[3];
    const float* w_hh_l0f = (const float*)d_in[4];
    const float* b_ih_l0f = (const float*)d_in[5];
    const float* b_hh_l0f = (const float*)d_in[6];
    const float* w_ih_l0b = (const float*)d_in[7];
    const float* w_hh_l0b = (const float*)d_in[8];
    const float* b_ih_l0b = (const float*)d_in[9];
    const float* b_hh_l0b = (const float*)d_in[10];
    const float* w_ih_l1f = (const float*)d_in[11];
    const float* w_hh_l1f = (const float*)d_in[12];
    const float* b_ih_l1f = (const float*)d_in[13];
    const float* b_hh_l1f = (const float*)d_in[14];
    const float* w_ih_l1b = (const float*)d_in[15];
    const float* w_hh_l1b = (const float*)d_in[16];
    const float* b_ih_l1b = (const float*)d_in[17];
    const float* b_hh_l1b = (const float*)d_in[18];
    const float* w_out    = (const float*)d_in[19];
    const float* b_out    = (const float*)d_in[20];
    const float* start_tr = (const float*)d_in[21];
    const float* end_tr   = (const float*)d_in[22];
    const float* trans    = (const float*)d_in[23];

    // workspace layout (floats)
    float* ws  = (float*)d_ws;
    float* x0  = ws;                       // [16384][256]  (later: em + hg + cnt overlays)
    float* x1  = x0 + 4194304;             // [16384][512]
    float* x2  = x1 + 8388608;             // [16384][512]
    float* Gf  = x2 + 8388608;             // [16384][1024]
    float* Gb  = Gf + 16777216;            // [16384][1024]
    float* W3  = Gb + 16777216;            // 4 x [16][256][64] packed W_hh
    float* W3l0f = W3, *W3l0b = W3 + 262144, *W3l1f = W3 + 524288, *W3l1b = W3 + 786432;
    float* em  = x0;                       // [16384][16], reuse x0 after layer-0 GEMMs
    float* hg  = x0 + 1048576;             // [16 dom][2 par][8][256] = 65536 floats
    int*   cnt = (int*)(x0 + 1179648);     // 2 layers x [16 dom][256 steps][32] = 262144 ints

    embed_kernel<<<16384, 64, 0, stream>>>(tokens, emb, x0);
    pack_w3_kernel<<<dim3(16, 16, 4), 256, 0, stream>>>(w_hh_l0f, w_hh_l0b, w_hh_l1f, w_hh_l1b, W3);

    dim3 gg(128, 8);
    gemm_bias_kernel<<<gg, 256, 0, stream>>>(x0, w_ih_l0f, b_ih_l0f, b_hh_l0f, Gf, 16384, 1024, 256);
    gemm_bias_kernel<<<gg, 256, 0, stream>>>(x0, w_ih_l0b, b_ih_l0b, b_hh_l0b, Gb, 16384, 1024, 256);
    init_cnt_kernel<<<1024, 256, 0, stream>>>(cnt);   // after x0 consumed, before scan0
    lstm_scan_kernel<<<256, 256, 0, stream>>>(Gf, Gb, W3l0f, W3l0b, lengths, x1, hg, cnt);

    gemm_bias_kernel<<<gg, 256, 0, stream>>>(x1, w_ih_l1f, b_ih_l1f, b_hh_l1f, Gf, 16384, 1024, 512);
    gemm_bias_kernel<<<gg, 256, 0, stream>>>(x1, w_ih_l1b, b_ih_l1b, b_hh_l1b, Gb, 16384, 1024, 512);
    lstm_scan_kernel<<<256, 256, 0, stream>>>(Gf, Gb, W3l1f, W3l1b, lengths, x2, hg, cnt + 131072);

    emis_kernel<<<1024, 256, 0, stream>>>(x2, w_out, b_out, em);
    viterbi_kernel<<<64, 64, 0, stream>>>(em, tokens, start_tr, end_tr, trans, (float*)d_out);
}